// Round 3
// baseline (896.843 us; speedup 1.0000x reference)
//
#include <hip/hip_runtime.h>

#define N_NODES 50000
#define N_EDGES 800000
#define HEADS 4
#define NUM_GRAPHS 8

// ============ CSR build ============
__global__ __launch_bounds__(256) void hist_kernel(const int* __restrict__ dst,
                                                   int* __restrict__ deg) {
  int e = blockIdx.x * blockDim.x + threadIdx.x;
  if (e < N_EDGES) atomicAdd(&deg[dst[e]], 1);
}

#define SCAN_T 1024
__global__ __launch_bounds__(SCAN_T) void scan_kernel(const int* __restrict__ deg,
                                                      int* __restrict__ rowstart,
                                                      int* __restrict__ cursor) {
  __shared__ int part[SCAN_T];
  int t = threadIdx.x;
  const int chunk = (N_NODES + SCAN_T - 1) / SCAN_T;  // 49
  int lo = t * chunk, hi = min(lo + chunk, N_NODES);
  int sum = 0;
  for (int i = lo; i < hi; i++) sum += deg[i];
  part[t] = sum;
  __syncthreads();
  for (int off = 1; off < SCAN_T; off <<= 1) {
    int v = part[t];
    int u = (t >= off) ? part[t - off] : 0;
    __syncthreads();
    part[t] = v + u;
    __syncthreads();
  }
  int base = (t == 0) ? 0 : part[t - 1];
  for (int i = lo; i < hi; i++) {
    rowstart[i] = base;
    cursor[i] = base;
    base += deg[i];
  }
  if (t == SCAN_T - 1) rowstart[N_NODES] = base;
}

// Writes perm[e] = CSR slot of edge e, and src_perm[slot] = src[e]
__global__ __launch_bounds__(256) void scatter_kernel(const int* __restrict__ src,
                                                      const int* __restrict__ dst,
                                                      int* __restrict__ cursor,
                                                      int* __restrict__ perm,
                                                      int* __restrict__ src_perm) {
  int e = blockIdx.x * blockDim.x + threadIdx.x;
  if (e >= N_EDGES) return;
  int p = atomicAdd(&cursor[dst[e]], 1);
  perm[e] = p;
  src_perm[p] = src[e];
}

// ============ fc0: h0 = relu(x@W0+b0) [N,16] ============
__global__ __launch_bounds__(256) void fc0_kernel(
    const float* __restrict__ x,
    const float* __restrict__ fc0_w, const float* __restrict__ fc0_b,
    float* __restrict__ h0) {
  __shared__ float sW0[3 * 16];
  __shared__ float sB0[16];
  for (int i = threadIdx.x; i < 48; i += blockDim.x) sW0[i] = fc0_w[i];
  for (int i = threadIdx.x; i < 16; i += blockDim.x) sB0[i] = fc0_b[i];
  __syncthreads();
  int n = blockIdx.x * blockDim.x + threadIdx.x;
  if (n >= N_NODES) return;
  float x0 = x[n * 3 + 0], x1 = x[n * 3 + 1], x2 = x[n * 3 + 2];
#pragma unroll
  for (int j = 0; j < 16; j++) {
    float v = x0 * sW0[0 * 16 + j] + x1 * sW0[1 * 16 + j] + x2 * sW0[2 * 16 + j] + sB0[j];
    h0[(size_t)n * 16 + j] = fmaxf(v, 0.f);
  }
}

// ============ Q kernel: per-edge head softmax, written in CSR-slot order ============
template <int CIN>
__global__ __launch_bounds__(256) void q_kernel(
    const int* __restrict__ src, const int* __restrict__ dst,
    const int* __restrict__ perm,
    const float* __restrict__ h,
    const float* __restrict__ u, const float* __restrict__ cb,
    float* __restrict__ q_perm) {
  int e = blockIdx.x * blockDim.x + threadIdx.x;
  if (e >= N_EDGES) return;
  int s = src[e];
  int d = dst[e];
  float t[CIN];
  const float4* hs4 = reinterpret_cast<const float4*>(h + (size_t)s * CIN);
  const float4* hd4 = reinterpret_cast<const float4*>(h + (size_t)d * CIN);
#pragma unroll
  for (int j = 0; j < CIN / 4; j++) {
    float4 a = hs4[j];
    float4 b = hd4[j];
    t[4 * j + 0] = a.x - b.x;
    t[4 * j + 1] = a.y - b.y;
    t[4 * j + 2] = a.z - b.z;
    t[4 * j + 3] = a.w - b.w;
  }
  float logit[HEADS];
#pragma unroll
  for (int hh = 0; hh < HEADS; hh++) {
    float acc = cb[hh];
#pragma unroll
    for (int j = 0; j < CIN; j++) acc += t[j] * u[j * HEADS + hh];
    logit[hh] = acc;
  }
  float m = fmaxf(fmaxf(logit[0], logit[1]), fmaxf(logit[2], logit[3]));
  float qv[HEADS];
  float ssum = 0.f;
#pragma unroll
  for (int hh = 0; hh < HEADS; hh++) {
    qv[hh] = __expf(logit[hh] - m);
    ssum += qv[hh];
  }
  float inv = 1.f / ssum;
  float4 outv = make_float4(qv[0] * inv, qv[1] * inv, qv[2] * inv, qv[3] * inv);
  *reinterpret_cast<float4*>(q_perm + 4 * (size_t)perm[e]) = outv;
}

// ============ Fused AGG+GEMM, layer 1 ============
// A[d,h,j] = sum_{e->d} q[e,h] * h0[src_e, j]   (CIN=16, 64 lanes/node, 4 nodes/block)
// h1[d,c]  = relu( (1/deg) * sum_{h,j} A[h,j]*W1[j, h*32+c] + b1[c] )
__global__ __launch_bounds__(256) void agg1_kernel(
    const int* __restrict__ rowstart, const int* __restrict__ src_perm,
    const float* __restrict__ q_perm, const float* __restrict__ h0,
    const float* __restrict__ w1, const float* __restrict__ b1,
    float* __restrict__ h1) {
  __shared__ float sW1[16 * 128];  // 8 KB
  __shared__ float sA[4][64];
  for (int i = threadIdx.x; i < 16 * 128; i += 256) sW1[i] = w1[i];
  int ln = threadIdx.x / 64;      // local node 0..3
  int l = threadIdx.x % 64;       // (h,j): h=l/16, j=l%16
  int hh = l / 16, j = l % 16;
  int node = blockIdx.x * 4 + ln;
  int e0 = rowstart[node], e1 = rowstart[node + 1];
  float acc = 0.f;
  for (int p = e0; p < e1; p++) {
    int s = src_perm[p];
    float qv = q_perm[4 * (size_t)p + hh];
    acc += qv * h0[(size_t)s * 16 + j];
  }
  sA[ln][l] = acc;
  __syncthreads();
  // GEMM phase: 128 threads = 4 nodes x 32 channels
  if (threadIdx.x < 128) {
    int ln2 = threadIdx.x / 32;
    int c = threadIdx.x % 32;
    int node2 = blockIdx.x * 4 + ln2;
    int d0 = rowstart[node2], d1 = rowstart[node2 + 1];
    float invn = 1.f / fmaxf((float)(d1 - d0), 1.f);
    float s = 0.f;
#pragma unroll
    for (int k = 0; k < 64; k++) {
      // k -> (h=k/16, j=k%16); W1[j, h*32+c]
      s += sA[ln2][k] * sW1[(k % 16) * 128 + (k / 16) * 32 + c];
    }
    h1[(size_t)node2 * 32 + c] = fmaxf(s * invn + b1[c], 0.f);
  }
}

// ============ Fused AGG+GEMM, layer 2 ============
// A[d,h,j] = sum_{e->d} q[e,h] * h1[src_e, j]   (CIN=32, 128 lanes/node, 2 nodes/block)
// h2[d,c]  = relu( (1/deg) * sum_{h,j} A[h,j]*W2[j, h*64+c] + b2[c] )
__global__ __launch_bounds__(256) void agg2_kernel(
    const int* __restrict__ rowstart, const int* __restrict__ src_perm,
    const float* __restrict__ q_perm, const float* __restrict__ h1,
    const float* __restrict__ w2, const float* __restrict__ b2,
    float* __restrict__ h2) {
  __shared__ float sW2[32 * 256];  // 32 KB
  __shared__ float sA[2][128];
  for (int i = threadIdx.x; i < 32 * 256; i += 256) sW2[i] = w2[i];
  int ln = threadIdx.x / 128;     // local node 0..1
  int l = threadIdx.x % 128;      // (h,j): h=l/32, j=l%32
  int hh = l / 32, j = l % 32;
  int node = blockIdx.x * 2 + ln;
  int e0 = rowstart[node], e1 = rowstart[node + 1];
  float acc = 0.f;
  for (int p = e0; p < e1; p++) {
    int s = src_perm[p];
    float qv = q_perm[4 * (size_t)p + hh];
    acc += qv * h1[(size_t)s * 32 + j];
  }
  sA[ln][l] = acc;
  __syncthreads();
  // GEMM phase: 128 threads = 2 nodes x 64 channels
  if (threadIdx.x < 128) {
    int ln2 = threadIdx.x / 64;
    int c = threadIdx.x % 64;
    int node2 = blockIdx.x * 2 + ln2;
    int d0 = rowstart[node2], d1 = rowstart[node2 + 1];
    float invn = 1.f / fmaxf((float)(d1 - d0), 1.f);
    float s = 0.f;
#pragma unroll
    for (int k = 0; k < 128; k++) {
      // k -> (h=k/32, j=k%32); W2[j, h*64+c]
      s += sA[ln2][k] * sW2[(k % 32) * 256 + (k / 32) * 64 + c];
    }
    h2[(size_t)node2 * 64 + c] = fmaxf(s * invn + b2[c], 0.f);
  }
}

// ============ Pool: per-graph mean of h2 (batch sorted) ============
#define POOL_CHUNK 512
__global__ __launch_bounds__(64) void pool_kernel(
    const float* __restrict__ h2, const int* __restrict__ batch,
    float* __restrict__ gsum, float* __restrict__ gcnt) {
  int c = threadIdx.x;  // 0..63
  int n0 = blockIdx.x * POOL_CHUNK;
  int n1 = min(n0 + POOL_CHUNK, N_NODES);
  if (n0 >= N_NODES) return;
  float acc = 0.f;
  float cacc = 0.f;
  int curg = batch[n0];
  for (int n = n0; n < n1; n++) {
    int g = batch[n];
    float v = h2[(size_t)n * 64 + c];
    if (g != curg) {
      atomicAdd(&gsum[curg * 64 + c], acc);
      if (c == 0) atomicAdd(&gcnt[curg], cacc);
      acc = 0.f;
      cacc = 0.f;
      curg = g;
    }
    acc += v;
    cacc += 1.f;
  }
  atomicAdd(&gsum[curg * 64 + c], acc);
  if (c == 0) atomicAdd(&gcnt[curg], cacc);
}

// ============ Head: out = (gsum/gcnt) @ fc1_w + fc1_b ============
__global__ __launch_bounds__(128) void head_kernel(
    const float* __restrict__ gsum, const float* __restrict__ gcnt,
    const float* __restrict__ fc1_w, const float* __restrict__ fc1_b,
    float* __restrict__ out) {
  int t = threadIdx.x;
  if (t >= NUM_GRAPHS * 10) return;
  int g = t / 10, k = t % 10;
  float inv = 1.f / fmaxf(gcnt[g], 1.f);
  float s = fc1_b[k];
#pragma unroll
  for (int c = 0; c < 64; c++) s += gsum[g * 64 + c] * inv * fc1_w[c * 10 + k];
  out[g * 10 + k] = s;
}

extern "C" void kernel_launch(void* const* d_in, const int* in_sizes, int n_in,
                              void* d_out, int out_size, void* d_ws, size_t ws_size,
                              hipStream_t stream) {
  const float* x = (const float*)d_in[0];
  const int* edge_index = (const int*)d_in[1];
  const int* batch = (const int*)d_in[2];
  const float* fc0_w = (const float*)d_in[3];
  const float* fc0_b = (const float*)d_in[4];
  const float* u1 = (const float*)d_in[5];
  const float* c1 = (const float*)d_in[6];
  const float* w1 = (const float*)d_in[7];
  const float* b1 = (const float*)d_in[8];
  const float* u2 = (const float*)d_in[9];
  const float* c2 = (const float*)d_in[10];
  const float* w2 = (const float*)d_in[11];
  const float* b2 = (const float*)d_in[12];
  const float* fc1_w = (const float*)d_in[13];
  const float* fc1_b = (const float*)d_in[14];
  float* out = (float*)d_out;

  const int* src = edge_index;            // x_j
  const int* dst = edge_index + N_EDGES;  // x_i

  // ---- workspace layout (units of 4 bytes; 16B alignment kept) ----
  char* wsb = (char*)d_ws;
  int* deg = (int*)wsb;                          // N
  int* rowstart = deg + N_NODES;                 // N+1
  int* cursor = rowstart + N_NODES + 1;          // N
  int* perm = cursor + N_NODES;                  // E
  int* src_perm = perm + N_EDGES;                // E
  // offset: 3*N+1+2*E = 150001 + 1600000 = 1750001 -> pad to 1750004
  float* q_perm = (float*)wsb + 1750004;         // E*4
  float* h0 = q_perm + (size_t)N_EDGES * 4;      // N*16
  float* h1 = h0 + (size_t)N_NODES * 16;         // N*32
  float* h2 = h1 + (size_t)N_NODES * 32;         // N*64
  float* gsum = h2 + (size_t)N_NODES * 64;       // 8*64
  float* gcnt = gsum + NUM_GRAPHS * 64;          // 8

  hipMemsetAsync(deg, 0, N_NODES * sizeof(int), stream);
  hipMemsetAsync(gsum, 0, (NUM_GRAPHS * 64 + NUM_GRAPHS) * sizeof(float), stream);

  int nblk = (N_NODES + 255) / 256;
  int eblk = (N_EDGES + 255) / 256;

  // CSR build (deg/rowstart/perm/src_perm)
  hist_kernel<<<eblk, 256, 0, stream>>>(dst, deg);
  scan_kernel<<<1, SCAN_T, 0, stream>>>(deg, rowstart, cursor);
  scatter_kernel<<<eblk, 256, 0, stream>>>(src, dst, cursor, perm, src_perm);

  // Layer 0
  fc0_kernel<<<nblk, 256, 0, stream>>>(x, fc0_w, fc0_b, h0);

  // FeaStConv 1
  q_kernel<16><<<eblk, 256, 0, stream>>>(src, dst, perm, h0, u1, c1, q_perm);
  agg1_kernel<<<(N_NODES + 3) / 4, 256, 0, stream>>>(rowstart, src_perm, q_perm, h0, w1, b1, h1);

  // FeaStConv 2
  q_kernel<32><<<eblk, 256, 0, stream>>>(src, dst, perm, h1, u2, c2, q_perm);
  agg2_kernel<<<(N_NODES + 1) / 2, 256, 0, stream>>>(rowstart, src_perm, q_perm, h1, w2, b2, h2);

  // Pool + head
  int pblk = (N_NODES + POOL_CHUNK - 1) / POOL_CHUNK;
  pool_kernel<<<pblk, 64, 0, stream>>>(h2, batch, gsum, gcnt);
  head_kernel<<<1, 128, 0, stream>>>(gsum, gcnt, fc1_w, fc1_b, out);
}

// Round 4
// 563.651 us; speedup vs baseline: 1.5911x; 1.5911x over previous
//
#include <hip/hip_runtime.h>

#define N_NODES 50000
#define N_EDGES 800000
#define HEADS 4
#define NUM_GRAPHS 8

// ============ CSR build ============
__global__ __launch_bounds__(256) void hist_kernel(const int* __restrict__ dst,
                                                   int* __restrict__ deg) {
  int e = blockIdx.x * blockDim.x + threadIdx.x;
  if (e < N_EDGES) atomicAdd(&deg[dst[e]], 1);
}

#define SCAN_T 1024
__global__ __launch_bounds__(SCAN_T) void scan_kernel(const int* __restrict__ deg,
                                                      int* __restrict__ rowstart,
                                                      int* __restrict__ cursor) {
  __shared__ int part[SCAN_T];
  int t = threadIdx.x;
  const int chunk = (N_NODES + SCAN_T - 1) / SCAN_T;  // 49
  int lo = t * chunk, hi = min(lo + chunk, N_NODES);
  int sum = 0;
  for (int i = lo; i < hi; i++) sum += deg[i];
  part[t] = sum;
  __syncthreads();
  for (int off = 1; off < SCAN_T; off <<= 1) {
    int v = part[t];
    int u = (t >= off) ? part[t - off] : 0;
    __syncthreads();
    part[t] = v + u;
    __syncthreads();
  }
  int base = (t == 0) ? 0 : part[t - 1];
  for (int i = lo; i < hi; i++) {
    rowstart[i] = base;
    cursor[i] = base;
    base += deg[i];
  }
  if (t == SCAN_T - 1) rowstart[N_NODES] = base;
}

// perm[e] = CSR slot of edge e; src_perm[slot] = src[e]
__global__ __launch_bounds__(256) void scatter_kernel(const int* __restrict__ src,
                                                      const int* __restrict__ dst,
                                                      int* __restrict__ cursor,
                                                      int* __restrict__ perm,
                                                      int* __restrict__ src_perm) {
  int e = blockIdx.x * blockDim.x + threadIdx.x;
  if (e >= N_EDGES) return;
  int p = atomicAdd(&cursor[dst[e]], 1);
  perm[e] = p;
  src_perm[p] = src[e];
}

// ============ fc0: h0 = relu(x@W0+b0) [N,16] ============
__global__ __launch_bounds__(256) void fc0_kernel(
    const float* __restrict__ x,
    const float* __restrict__ fc0_w, const float* __restrict__ fc0_b,
    float* __restrict__ h0) {
  __shared__ float sW0[3 * 16];
  __shared__ float sB0[16];
  for (int i = threadIdx.x; i < 48; i += blockDim.x) sW0[i] = fc0_w[i];
  for (int i = threadIdx.x; i < 16; i += blockDim.x) sB0[i] = fc0_b[i];
  __syncthreads();
  int n = blockIdx.x * blockDim.x + threadIdx.x;
  if (n >= N_NODES) return;
  float x0 = x[n * 3 + 0], x1 = x[n * 3 + 1], x2 = x[n * 3 + 2];
#pragma unroll
  for (int j = 0; j < 16; j++) {
    float v = x0 * sW0[0 * 16 + j] + x1 * sW0[1 * 16 + j] + x2 * sW0[2 * 16 + j] + sB0[j];
    h0[(size_t)n * 16 + j] = fmaxf(v, 0.f);
  }
}

// ============ Q kernel: per-edge head softmax, written in CSR-slot order ============
template <int CIN>
__global__ __launch_bounds__(256) void q_kernel(
    const int* __restrict__ src, const int* __restrict__ dst,
    const int* __restrict__ perm,
    const float* __restrict__ h,
    const float* __restrict__ u, const float* __restrict__ cb,
    float* __restrict__ q_perm) {
  int e = blockIdx.x * blockDim.x + threadIdx.x;
  if (e >= N_EDGES) return;
  int s = src[e];
  int d = dst[e];
  float t[CIN];
  const float4* hs4 = reinterpret_cast<const float4*>(h + (size_t)s * CIN);
  const float4* hd4 = reinterpret_cast<const float4*>(h + (size_t)d * CIN);
#pragma unroll
  for (int j = 0; j < CIN / 4; j++) {
    float4 a = hs4[j];
    float4 b = hd4[j];
    t[4 * j + 0] = a.x - b.x;
    t[4 * j + 1] = a.y - b.y;
    t[4 * j + 2] = a.z - b.z;
    t[4 * j + 3] = a.w - b.w;
  }
  float logit[HEADS];
#pragma unroll
  for (int hh = 0; hh < HEADS; hh++) {
    float acc = cb[hh];
#pragma unroll
    for (int j = 0; j < CIN; j++) acc += t[j] * u[j * HEADS + hh];
    logit[hh] = acc;
  }
  float m = fmaxf(fmaxf(logit[0], logit[1]), fmaxf(logit[2], logit[3]));
  float qv[HEADS];
  float ssum = 0.f;
#pragma unroll
  for (int hh = 0; hh < HEADS; hh++) {
    qv[hh] = __expf(logit[hh] - m);
    ssum += qv[hh];
  }
  float inv = 1.f / ssum;
  float4 outv = make_float4(qv[0] * inv, qv[1] * inv, qv[2] * inv, qv[3] * inv);
  *reinterpret_cast<float4*>(q_perm + 4 * (size_t)perm[e]) = outv;
}

// ============ AGG: A[node, h*CIN+j] = sum_{e->node} q[e,h] * h[src_e, j] ============
// No LDS, no barrier; 4*CIN lanes per node; edge loop unrolled x4 for 4
// independent gather chains (latency hiding).
template <int CIN>
__global__ __launch_bounds__(256) void agg_kernel(
    const int* __restrict__ rowstart, const int* __restrict__ src_perm,
    const float* __restrict__ q_perm, const float* __restrict__ h,
    float* __restrict__ A) {
  constexpr int L = 4 * CIN;
  constexpr int NPB = 256 / L;
  int ln = threadIdx.x / L;
  int l = threadIdx.x % L;
  int hh = l / CIN, j = l % CIN;
  int node = blockIdx.x * NPB + ln;
  if (node >= N_NODES) return;
  int e0 = rowstart[node], e1 = rowstart[node + 1];
  float acc = 0.f;
  int p = e0;
  for (; p + 4 <= e1; p += 4) {
    int s0 = src_perm[p + 0];
    int s1 = src_perm[p + 1];
    int s2 = src_perm[p + 2];
    int s3 = src_perm[p + 3];
    float q0 = q_perm[4 * (p + 0) + hh];
    float q1 = q_perm[4 * (p + 1) + hh];
    float q2 = q_perm[4 * (p + 2) + hh];
    float q3 = q_perm[4 * (p + 3) + hh];
    float f0 = h[s0 * CIN + j];
    float f1 = h[s1 * CIN + j];
    float f2 = h[s2 * CIN + j];
    float f3 = h[s3 * CIN + j];
    acc += q0 * f0 + q1 * f1 + q2 * f2 + q3 * f3;
  }
  for (; p < e1; p++) {
    int s = src_perm[p];
    acc += q_perm[4 * p + hh] * h[s * CIN + j];
  }
  A[(size_t)node * L + l] = acc;
}

// ============ GEMM1: h1 = relu((A1 @ B1)/deg + b1), A1:[N,64], B1:[64,32] ============
// B1[hj][c] = w1[j*128 + h*32 + c] (hj = h*16+j). Block: 256 thr = 8 nodes x 32 ch,
// loops 8 node-tiles (64 nodes/block) to amortize the LDS stage.
__global__ __launch_bounds__(256) void gemm1_kernel(
    const int* __restrict__ rowstart, const float* __restrict__ A,
    const float* __restrict__ w1, const float* __restrict__ b1,
    float* __restrict__ h1) {
  __shared__ float sB[64 * 32];  // 8 KB
  for (int i = threadIdx.x; i < 64 * 32; i += 256) {
    int hj = i / 32, c = i % 32;
    int hh = hj / 16, j = hj % 16;
    sB[i] = w1[j * 128 + hh * 32 + c];
  }
  __syncthreads();
  int c = threadIdx.x % 32;
  float bc = b1[c];
#pragma unroll
  for (int t = 0; t < 8; t++) {
    int node = blockIdx.x * 64 + t * 8 + threadIdx.x / 32;
    if (node < N_NODES) {
      const float4* Ar = reinterpret_cast<const float4*>(A + (size_t)node * 64);
      float acc = 0.f;
#pragma unroll
      for (int k4 = 0; k4 < 16; k4++) {
        float4 a = Ar[k4];
        acc += a.x * sB[(4 * k4 + 0) * 32 + c];
        acc += a.y * sB[(4 * k4 + 1) * 32 + c];
        acc += a.z * sB[(4 * k4 + 2) * 32 + c];
        acc += a.w * sB[(4 * k4 + 3) * 32 + c];
      }
      int d = rowstart[node + 1] - rowstart[node];
      float invn = 1.f / fmaxf((float)d, 1.f);
      h1[(size_t)node * 32 + c] = fmaxf(acc * invn + bc, 0.f);
    }
  }
}

// ============ GEMM2: h2 = relu((A2 @ B2)/deg + b2), A2:[N,128], B2:[128,64] ============
// B2[hj][c] = w2[j*256 + h*64 + c] (hj = h*32+j). Block: 256 thr = 4 nodes x 64 ch,
// loops 8 node-tiles (32 nodes/block).
__global__ __launch_bounds__(256) void gemm2_kernel(
    const int* __restrict__ rowstart, const float* __restrict__ A,
    const float* __restrict__ w2, const float* __restrict__ b2,
    float* __restrict__ h2) {
  __shared__ float sB[128 * 64];  // 32 KB
  for (int i = threadIdx.x; i < 128 * 64; i += 256) {
    int hj = i / 64, c = i % 64;
    int hh = hj / 32, j = hj % 32;
    sB[i] = w2[j * 256 + hh * 64 + c];
  }
  __syncthreads();
  int c = threadIdx.x % 64;
  float bc = b2[c];
#pragma unroll
  for (int t = 0; t < 8; t++) {
    int node = blockIdx.x * 32 + t * 4 + threadIdx.x / 64;
    if (node < N_NODES) {
      const float4* Ar = reinterpret_cast<const float4*>(A + (size_t)node * 128);
      float acc = 0.f;
#pragma unroll
      for (int k4 = 0; k4 < 32; k4++) {
        float4 a = Ar[k4];
        acc += a.x * sB[(4 * k4 + 0) * 64 + c];
        acc += a.y * sB[(4 * k4 + 1) * 64 + c];
        acc += a.z * sB[(4 * k4 + 2) * 64 + c];
        acc += a.w * sB[(4 * k4 + 3) * 64 + c];
      }
      int d = rowstart[node + 1] - rowstart[node];
      float invn = 1.f / fmaxf((float)d, 1.f);
      h2[(size_t)node * 64 + c] = fmaxf(acc * invn + bc, 0.f);
    }
  }
}

// ============ Pool: per-graph mean of h2 (batch sorted) ============
// 256 threads = 4 groups of 64 lanes; each group handles a chunk of nodes.
#define POOL_CHUNK 64
__global__ __launch_bounds__(256) void pool_kernel(
    const float* __restrict__ h2, const int* __restrict__ batch,
    float* __restrict__ gsum, float* __restrict__ gcnt) {
  int grp = threadIdx.x / 64;
  int c = threadIdx.x % 64;
  int n0 = (blockIdx.x * 4 + grp) * POOL_CHUNK;
  int n1 = min(n0 + POOL_CHUNK, N_NODES);
  if (n0 >= N_NODES) return;
  float acc = 0.f;
  float cacc = 0.f;
  int curg = batch[n0];
  for (int n = n0; n < n1; n++) {
    int g = batch[n];
    float v = h2[(size_t)n * 64 + c];
    if (g != curg) {
      atomicAdd(&gsum[curg * 64 + c], acc);
      if (c == 0) atomicAdd(&gcnt[curg], cacc);
      acc = 0.f;
      cacc = 0.f;
      curg = g;
    }
    acc += v;
    cacc += 1.f;
  }
  atomicAdd(&gsum[curg * 64 + c], acc);
  if (c == 0) atomicAdd(&gcnt[curg], cacc);
}

// ============ Head: out = (gsum/gcnt) @ fc1_w + fc1_b ============
__global__ __launch_bounds__(128) void head_kernel(
    const float* __restrict__ gsum, const float* __restrict__ gcnt,
    const float* __restrict__ fc1_w, const float* __restrict__ fc1_b,
    float* __restrict__ out) {
  int t = threadIdx.x;
  if (t >= NUM_GRAPHS * 10) return;
  int g = t / 10, k = t % 10;
  float inv = 1.f / fmaxf(gcnt[g], 1.f);
  float s = fc1_b[k];
#pragma unroll
  for (int c = 0; c < 64; c++) s += gsum[g * 64 + c] * inv * fc1_w[c * 10 + k];
  out[g * 10 + k] = s;
}

extern "C" void kernel_launch(void* const* d_in, const int* in_sizes, int n_in,
                              void* d_out, int out_size, void* d_ws, size_t ws_size,
                              hipStream_t stream) {
  const float* x = (const float*)d_in[0];
  const int* edge_index = (const int*)d_in[1];
  const int* batch = (const int*)d_in[2];
  const float* fc0_w = (const float*)d_in[3];
  const float* fc0_b = (const float*)d_in[4];
  const float* u1 = (const float*)d_in[5];
  const float* c1 = (const float*)d_in[6];
  const float* w1 = (const float*)d_in[7];
  const float* b1 = (const float*)d_in[8];
  const float* u2 = (const float*)d_in[9];
  const float* c2 = (const float*)d_in[10];
  const float* w2 = (const float*)d_in[11];
  const float* b2 = (const float*)d_in[12];
  const float* fc1_w = (const float*)d_in[13];
  const float* fc1_b = (const float*)d_in[14];
  float* out = (float*)d_out;

  const int* src = edge_index;            // x_j
  const int* dst = edge_index + N_EDGES;  // x_i

  // ---- workspace layout (4-byte words; all region starts 16B-aligned) ----
  char* wsb = (char*)d_ws;
  int* deg = (int*)wsb;                          // N
  int* rowstart = deg + N_NODES;                 // N+1
  int* cursor = rowstart + N_NODES + 1;          // N
  int* perm = cursor + N_NODES;                  // E
  int* src_perm = perm + N_EDGES;                // E
  // words so far: 3N+1+2E = 1750001 -> pad to 1750004
  float* q_perm = (float*)wsb + 1750004;         // E*4
  float* h0 = q_perm + (size_t)N_EDGES * 4;      // N*16
  float* h1 = h0 + (size_t)N_NODES * 16;         // N*32
  float* h2 = h1 + (size_t)N_NODES * 32;         // N*64
  float* A = h2 + (size_t)N_NODES * 64;          // N*128 (shared by layer 1 & 2)
  float* gsum = A + (size_t)N_NODES * 128;       // 8*64
  float* gcnt = gsum + NUM_GRAPHS * 64;          // 8

  hipMemsetAsync(deg, 0, N_NODES * sizeof(int), stream);
  hipMemsetAsync(gsum, 0, (NUM_GRAPHS * 64 + NUM_GRAPHS) * sizeof(float), stream);

  int nblk = (N_NODES + 255) / 256;
  int eblk = (N_EDGES + 255) / 256;

  // CSR build
  hist_kernel<<<eblk, 256, 0, stream>>>(dst, deg);
  scan_kernel<<<1, SCAN_T, 0, stream>>>(deg, rowstart, cursor);
  scatter_kernel<<<eblk, 256, 0, stream>>>(src, dst, cursor, perm, src_perm);

  // Layer 0
  fc0_kernel<<<nblk, 256, 0, stream>>>(x, fc0_w, fc0_b, h0);

  // FeaStConv 1: q -> A[N,64] -> h1[N,32]
  q_kernel<16><<<eblk, 256, 0, stream>>>(src, dst, perm, h0, u1, c1, q_perm);
  agg_kernel<16><<<(N_NODES + 3) / 4, 256, 0, stream>>>(rowstart, src_perm, q_perm, h0, A);
  gemm1_kernel<<<(N_NODES + 63) / 64, 256, 0, stream>>>(rowstart, A, w1, b1, h1);

  // FeaStConv 2: q -> A[N,128] -> h2[N,64]
  q_kernel<32><<<eblk, 256, 0, stream>>>(src, dst, perm, h1, u2, c2, q_perm);
  agg_kernel<32><<<(N_NODES + 1) / 2, 256, 0, stream>>>(rowstart, src_perm, q_perm, h1, A);
  gemm2_kernel<<<(N_NODES + 31) / 32, 256, 0, stream>>>(rowstart, A, w2, b2, h2);

  // Pool + head
  int pblk = (N_NODES + POOL_CHUNK * 4 - 1) / (POOL_CHUNK * 4);
  pool_kernel<<<pblk, 256, 0, stream>>>(h2, batch, gsum, gcnt);
  head_kernel<<<1, 128, 0, stream>>>(gsum, gcnt, fc1_w, fc1_b, out);
}

// Round 5
// 472.839 us; speedup vs baseline: 1.8967x; 1.1921x over previous
//
#include <hip/hip_runtime.h>

#define N_NODES 50000
#define N_EDGES 800000
#define HEADS 4
#define NUM_GRAPHS 8

// ============ CSR build ============
__global__ __launch_bounds__(256) void hist_kernel(const int* __restrict__ dst,
                                                   int* __restrict__ deg) {
  int e = blockIdx.x * blockDim.x + threadIdx.x;
  if (e < N_EDGES) atomicAdd(&deg[dst[e]], 1);
}

// Wave-aggregated bump allocation: rowstart[i] = arbitrary contiguous segment
// of length deg[i]. Order across nodes is irrelevant for correctness.
__global__ __launch_bounds__(256) void alloc_kernel(const int* __restrict__ deg,
                                                    int* __restrict__ gctr,
                                                    int* __restrict__ rowstart,
                                                    int* __restrict__ cursor) {
  int i = blockIdx.x * blockDim.x + threadIdx.x;
  int lane = threadIdx.x & 63;
  int d = (i < N_NODES) ? deg[i] : 0;
  // inclusive prefix over 64 lanes
  int pre = d;
#pragma unroll
  for (int off = 1; off < 64; off <<= 1) {
    int v = __shfl_up(pre, off, 64);
    if (lane >= off) pre += v;
  }
  int total = __shfl(pre, 63, 64);
  int base = 0;
  if (lane == 63) base = atomicAdd(gctr, total);
  base = __shfl(base, 63, 64);
  if (i < N_NODES) {
    int start = base + pre - d;
    rowstart[i] = start;
    cursor[i] = start;
  }
}

// perm[e] = CSR slot of edge e; src_perm[slot] = src[e]
__global__ __launch_bounds__(256) void scatter_kernel(const int* __restrict__ src,
                                                      const int* __restrict__ dst,
                                                      int* __restrict__ cursor,
                                                      int* __restrict__ perm,
                                                      int* __restrict__ src_perm) {
  int e = blockIdx.x * blockDim.x + threadIdx.x;
  if (e >= N_EDGES) return;
  int p = atomicAdd(&cursor[dst[e]], 1);
  perm[e] = p;
  src_perm[p] = src[e];
}

// ============ fc0: h0 = relu(x@W0+b0) [N,16] ============
__global__ __launch_bounds__(256) void fc0_kernel(
    const float* __restrict__ x,
    const float* __restrict__ fc0_w, const float* __restrict__ fc0_b,
    float* __restrict__ h0) {
  __shared__ float sW0[3 * 16];
  __shared__ float sB0[16];
  for (int i = threadIdx.x; i < 48; i += blockDim.x) sW0[i] = fc0_w[i];
  for (int i = threadIdx.x; i < 16; i += blockDim.x) sB0[i] = fc0_b[i];
  __syncthreads();
  int n = blockIdx.x * blockDim.x + threadIdx.x;
  if (n >= N_NODES) return;
  float x0 = x[n * 3 + 0], x1 = x[n * 3 + 1], x2 = x[n * 3 + 2];
#pragma unroll
  for (int j = 0; j < 16; j++) {
    float v = x0 * sW0[0 * 16 + j] + x1 * sW0[1 * 16 + j] + x2 * sW0[2 * 16 + j] + sB0[j];
    h0[(size_t)n * 16 + j] = fmaxf(v, 0.f);
  }
}

// ============ Q kernel: per-edge head softmax, written in CSR-slot order ============
template <int CIN>
__global__ __launch_bounds__(256) void q_kernel(
    const int* __restrict__ src, const int* __restrict__ dst,
    const int* __restrict__ perm,
    const float* __restrict__ h,
    const float* __restrict__ u, const float* __restrict__ cb,
    float* __restrict__ q_perm) {
  int e = blockIdx.x * blockDim.x + threadIdx.x;
  if (e >= N_EDGES) return;
  int s = src[e];
  int d = dst[e];
  float t[CIN];
  const float4* hs4 = reinterpret_cast<const float4*>(h + (size_t)s * CIN);
  const float4* hd4 = reinterpret_cast<const float4*>(h + (size_t)d * CIN);
#pragma unroll
  for (int j = 0; j < CIN / 4; j++) {
    float4 a = hs4[j];
    float4 b = hd4[j];
    t[4 * j + 0] = a.x - b.x;
    t[4 * j + 1] = a.y - b.y;
    t[4 * j + 2] = a.z - b.z;
    t[4 * j + 3] = a.w - b.w;
  }
  float logit[HEADS];
#pragma unroll
  for (int hh = 0; hh < HEADS; hh++) {
    float acc = cb[hh];
#pragma unroll
    for (int j = 0; j < CIN; j++) acc += t[j] * u[j * HEADS + hh];
    logit[hh] = acc;
  }
  float m = fmaxf(fmaxf(logit[0], logit[1]), fmaxf(logit[2], logit[3]));
  float qv[HEADS];
  float ssum = 0.f;
#pragma unroll
  for (int hh = 0; hh < HEADS; hh++) {
    qv[hh] = __expf(logit[hh] - m);
    ssum += qv[hh];
  }
  float inv = 1.f / ssum;
  float4 outv = make_float4(qv[0] * inv, qv[1] * inv, qv[2] * inv, qv[3] * inv);
  *reinterpret_cast<float4*>(q_perm + 4 * (size_t)perm[e]) = outv;
}

// ============ AGG: A[node, h*CIN+j] = sum_{e->node} q[e,h] * h[src_e, j] ============
// No LDS, no barrier; 4*CIN lanes per node; edge loop unrolled x4 for 4
// independent gather chains (latency hiding).
template <int CIN>
__global__ __launch_bounds__(256) void agg_kernel(
    const int* __restrict__ rowstart, const int* __restrict__ deg,
    const int* __restrict__ src_perm,
    const float* __restrict__ q_perm, const float* __restrict__ h,
    float* __restrict__ A) {
  constexpr int L = 4 * CIN;
  constexpr int NPB = 256 / L;
  int ln = threadIdx.x / L;
  int l = threadIdx.x % L;
  int hh = l / CIN, j = l % CIN;
  int node = blockIdx.x * NPB + ln;
  if (node >= N_NODES) return;
  int e0 = rowstart[node];
  int e1 = e0 + deg[node];
  float acc = 0.f;
  int p = e0;
  for (; p + 4 <= e1; p += 4) {
    int s0 = src_perm[p + 0];
    int s1 = src_perm[p + 1];
    int s2 = src_perm[p + 2];
    int s3 = src_perm[p + 3];
    float q0 = q_perm[4 * (p + 0) + hh];
    float q1 = q_perm[4 * (p + 1) + hh];
    float q2 = q_perm[4 * (p + 2) + hh];
    float q3 = q_perm[4 * (p + 3) + hh];
    float f0 = h[s0 * CIN + j];
    float f1 = h[s1 * CIN + j];
    float f2 = h[s2 * CIN + j];
    float f3 = h[s3 * CIN + j];
    acc += q0 * f0 + q1 * f1 + q2 * f2 + q3 * f3;
  }
  for (; p < e1; p++) {
    int s = src_perm[p];
    acc += q_perm[4 * p + hh] * h[s * CIN + j];
  }
  A[(size_t)node * L + l] = acc;
}

// ============ GEMM1: h1 = relu((A1 @ B1)/deg + b1), A1:[N,64], B1:[64,32] ============
__global__ __launch_bounds__(256) void gemm1_kernel(
    const int* __restrict__ deg, const float* __restrict__ A,
    const float* __restrict__ w1, const float* __restrict__ b1,
    float* __restrict__ h1) {
  __shared__ float sB[64 * 32];  // 8 KB
  for (int i = threadIdx.x; i < 64 * 32; i += 256) {
    int hj = i / 32, c = i % 32;
    int hh = hj / 16, j = hj % 16;
    sB[i] = w1[j * 128 + hh * 32 + c];
  }
  __syncthreads();
  int c = threadIdx.x % 32;
  float bc = b1[c];
#pragma unroll
  for (int t = 0; t < 8; t++) {
    int node = blockIdx.x * 64 + t * 8 + threadIdx.x / 32;
    if (node < N_NODES) {
      const float4* Ar = reinterpret_cast<const float4*>(A + (size_t)node * 64);
      float acc = 0.f;
#pragma unroll
      for (int k4 = 0; k4 < 16; k4++) {
        float4 a = Ar[k4];
        acc += a.x * sB[(4 * k4 + 0) * 32 + c];
        acc += a.y * sB[(4 * k4 + 1) * 32 + c];
        acc += a.z * sB[(4 * k4 + 2) * 32 + c];
        acc += a.w * sB[(4 * k4 + 3) * 32 + c];
      }
      float invn = 1.f / fmaxf((float)deg[node], 1.f);
      h1[(size_t)node * 32 + c] = fmaxf(acc * invn + bc, 0.f);
    }
  }
}

// ============ GEMM2: h2 = relu((A2 @ B2)/deg + b2), A2:[N,128], B2:[128,64] ============
__global__ __launch_bounds__(256) void gemm2_kernel(
    const int* __restrict__ deg, const float* __restrict__ A,
    const float* __restrict__ w2, const float* __restrict__ b2,
    float* __restrict__ h2) {
  __shared__ float sB[128 * 64];  // 32 KB
  for (int i = threadIdx.x; i < 128 * 64; i += 256) {
    int hj = i / 64, c = i % 64;
    int hh = hj / 32, j = hj % 32;
    sB[i] = w2[j * 256 + hh * 64 + c];
  }
  __syncthreads();
  int c = threadIdx.x % 64;
  float bc = b2[c];
#pragma unroll
  for (int t = 0; t < 8; t++) {
    int node = blockIdx.x * 32 + t * 4 + threadIdx.x / 64;
    if (node < N_NODES) {
      const float4* Ar = reinterpret_cast<const float4*>(A + (size_t)node * 128);
      float acc = 0.f;
#pragma unroll
      for (int k4 = 0; k4 < 32; k4++) {
        float4 a = Ar[k4];
        acc += a.x * sB[(4 * k4 + 0) * 64 + c];
        acc += a.y * sB[(4 * k4 + 1) * 64 + c];
        acc += a.z * sB[(4 * k4 + 2) * 64 + c];
        acc += a.w * sB[(4 * k4 + 3) * 64 + c];
      }
      float invn = 1.f / fmaxf((float)deg[node], 1.f);
      h2[(size_t)node * 64 + c] = fmaxf(acc * invn + bc, 0.f);
    }
  }
}

// ============ Pool: per-graph mean of h2 (batch sorted) ============
#define POOL_CHUNK 64
__global__ __launch_bounds__(256) void pool_kernel(
    const float* __restrict__ h2, const int* __restrict__ batch,
    float* __restrict__ gsum, float* __restrict__ gcnt) {
  int grp = threadIdx.x / 64;
  int c = threadIdx.x % 64;
  int n0 = (blockIdx.x * 4 + grp) * POOL_CHUNK;
  int n1 = min(n0 + POOL_CHUNK, N_NODES);
  if (n0 >= N_NODES) return;
  float acc = 0.f;
  float cacc = 0.f;
  int curg = batch[n0];
  for (int n = n0; n < n1; n++) {
    int g = batch[n];
    float v = h2[(size_t)n * 64 + c];
    if (g != curg) {
      atomicAdd(&gsum[curg * 64 + c], acc);
      if (c == 0) atomicAdd(&gcnt[curg], cacc);
      acc = 0.f;
      cacc = 0.f;
      curg = g;
    }
    acc += v;
    cacc += 1.f;
  }
  atomicAdd(&gsum[curg * 64 + c], acc);
  if (c == 0) atomicAdd(&gcnt[curg], cacc);
}

// ============ Head: out = (gsum/gcnt) @ fc1_w + fc1_b ============
__global__ __launch_bounds__(128) void head_kernel(
    const float* __restrict__ gsum, const float* __restrict__ gcnt,
    const float* __restrict__ fc1_w, const float* __restrict__ fc1_b,
    float* __restrict__ out) {
  int t = threadIdx.x;
  if (t >= NUM_GRAPHS * 10) return;
  int g = t / 10, k = t % 10;
  float inv = 1.f / fmaxf(gcnt[g], 1.f);
  float s = fc1_b[k];
#pragma unroll
  for (int c = 0; c < 64; c++) s += gsum[g * 64 + c] * inv * fc1_w[c * 10 + k];
  out[g * 10 + k] = s;
}

extern "C" void kernel_launch(void* const* d_in, const int* in_sizes, int n_in,
                              void* d_out, int out_size, void* d_ws, size_t ws_size,
                              hipStream_t stream) {
  const float* x = (const float*)d_in[0];
  const int* edge_index = (const int*)d_in[1];
  const int* batch = (const int*)d_in[2];
  const float* fc0_w = (const float*)d_in[3];
  const float* fc0_b = (const float*)d_in[4];
  const float* u1 = (const float*)d_in[5];
  const float* c1 = (const float*)d_in[6];
  const float* w1 = (const float*)d_in[7];
  const float* b1 = (const float*)d_in[8];
  const float* u2 = (const float*)d_in[9];
  const float* c2 = (const float*)d_in[10];
  const float* w2 = (const float*)d_in[11];
  const float* b2 = (const float*)d_in[12];
  const float* fc1_w = (const float*)d_in[13];
  const float* fc1_b = (const float*)d_in[14];
  float* out = (float*)d_out;

  const int* src = edge_index;            // x_j
  const int* dst = edge_index + N_EDGES;  // x_i

  // ---- workspace layout (4-byte words) ----
  char* wsb = (char*)d_ws;
  int* deg = (int*)wsb;                          // N       [memset with gctr]
  int* gctr = deg + N_NODES;                     // 1
  // pad to 50004
  int* rowstart = (int*)wsb + 50004;             // N
  int* cursor = rowstart + N_NODES;              // N
  int* perm = cursor + N_NODES;                  // E
  int* src_perm = perm + N_EDGES;                // E
  // words: 50004 + 2N + 2E = 1750004 -> already 4-aligned
  float* q_perm = (float*)wsb + 1750004;         // E*4
  float* h0 = q_perm + (size_t)N_EDGES * 4;      // N*16
  float* h1 = h0 + (size_t)N_NODES * 16;         // N*32
  float* h2 = h1 + (size_t)N_NODES * 32;         // N*64
  float* A = h2 + (size_t)N_NODES * 64;          // N*128 (shared by layer 1 & 2)
  float* gsum = A + (size_t)N_NODES * 128;       // 8*64
  float* gcnt = gsum + NUM_GRAPHS * 64;          // 8

  hipMemsetAsync(deg, 0, (N_NODES + 1) * sizeof(int), stream);  // deg + gctr
  hipMemsetAsync(gsum, 0, (NUM_GRAPHS * 64 + NUM_GRAPHS) * sizeof(float), stream);

  int nblk = (N_NODES + 255) / 256;
  int eblk = (N_EDGES + 255) / 256;

  // CSR build (unordered segment allocation)
  hist_kernel<<<eblk, 256, 0, stream>>>(dst, deg);
  alloc_kernel<<<nblk, 256, 0, stream>>>(deg, gctr, rowstart, cursor);
  scatter_kernel<<<eblk, 256, 0, stream>>>(src, dst, cursor, perm, src_perm);

  // Layer 0
  fc0_kernel<<<nblk, 256, 0, stream>>>(x, fc0_w, fc0_b, h0);

  // FeaStConv 1: q -> A[N,64] -> h1[N,32]
  q_kernel<16><<<eblk, 256, 0, stream>>>(src, dst, perm, h0, u1, c1, q_perm);
  agg_kernel<16><<<(N_NODES + 3) / 4, 256, 0, stream>>>(rowstart, deg, src_perm, q_perm, h0, A);
  gemm1_kernel<<<(N_NODES + 63) / 64, 256, 0, stream>>>(deg, A, w1, b1, h1);

  // FeaStConv 2: q -> A[N,128] -> h2[N,64]
  q_kernel<32><<<eblk, 256, 0, stream>>>(src, dst, perm, h1, u2, c2, q_perm);
  agg_kernel<32><<<(N_NODES + 1) / 2, 256, 0, stream>>>(rowstart, deg, src_perm, q_perm, h1, A);
  gemm2_kernel<<<(N_NODES + 31) / 32, 256, 0, stream>>>(deg, A, w2, b2, h2);

  // Pool + head
  int pblk = (N_NODES + POOL_CHUNK * 4 - 1) / (POOL_CHUNK * 4);
  pool_kernel<<<pblk, 256, 0, stream>>>(h2, batch, gsum, gcnt);
  head_kernel<<<1, 128, 0, stream>>>(gsum, gcnt, fc1_w, fc1_b, out);
}